// Round 2
// baseline (998.250 us; speedup 1.0000x reference)
//
#include <hip/hip_runtime.h>
#include <hip/hip_bf16.h>

// MoE top-2: T=8192 tokens, D=1024, F=4096, E=8.
// Pipeline: fused transpose-cast -> router -> gather -> GEMM1(gelu) -> GEMM2(gated P) -> combine.
// GEMMs: 256x256 8-phase schedule (T1 XCD-swizzle + T2 LDS swizzle + T3/T4 counted-vmcnt + T5 setprio).

#define T_TOK 8192
#define DDIM  1024
#define FDIM  4096
#define NEXP  8
#define RTOT  (T_TOK * 2)      // total assigned rows (top-2, always exactly 2T)
#define RPAD  (RTOT + 256)     // slack so 256-row tile staging can over-read harmlessly

#define BM 256
#define BN 256
#define BK 64

typedef __bf16 bf16x8 __attribute__((ext_vector_type(8)));
typedef float  f32x4  __attribute__((ext_vector_type(4)));

__device__ __forceinline__ float gelu_tanh(float x) {
  // 0.5x(1+tanh(u)) == x * sigmoid(2u); u = sqrt(2/pi)(x + 0.044715 x^3)
  float u = 0.7978845608028654f * (x + 0.044715f * x * x * x);
  return __fdividef(x, 1.f + __expf(-2.f * u));
}

#define GLOBAL_TO_LDS16(gp, lp)                                                   \
  __builtin_amdgcn_global_load_lds((const __attribute__((address_space(1))) void*)(gp), \
                                   (__attribute__((address_space(3))) void*)(lp), 16, 0, 0)

// ---------------- fused transpose+cast for w1 and w2 ----------------
// fp32 [E][Rr][Cc] -> bf16 [E][Cc][Rr]. float4 loads, 16B bf16 stores.
__global__ __launch_bounds__(256) void transpose_cast_both(const float* __restrict__ w1,
                                                           const float* __restrict__ w2,
                                                           __hip_bfloat16* __restrict__ w1t,
                                                           __hip_bfloat16* __restrict__ w2t) {
  __shared__ __hip_bfloat16 tile[64 * 66];
  int bid = blockIdx.x;
  const float* in; __hip_bfloat16* outp; int Rr, Cc;
  if (bid < NEXP * 1024) { in = w1; outp = w1t; Rr = DDIM; Cc = FDIM; }
  else { bid -= NEXP * 1024; in = w2; outp = w2t; Rr = FDIM; Cc = DDIM; }
  int tilesC = Cc >> 6;
  int per = (Rr >> 6) * tilesC;  // == 1024
  int e = bid / per, rem = bid % per;
  int tr = rem / tilesC, tc = rem % tilesC;
  const float* ip = in + (size_t)e * Rr * Cc + (size_t)(tr * 64) * Cc + tc * 64;
  __hip_bfloat16* op = outp + (size_t)e * Rr * Cc + (size_t)(tc * 64) * Rr + tr * 64;
  int tid = threadIdx.x;
  int lrow = tid >> 4, lcol = (tid & 15) * 4;
#pragma unroll
  for (int p = 0; p < 4; p++) {
    int r = p * 16 + lrow;
    float4 v = *(const float4*)(ip + (size_t)r * Cc + lcol);
    tile[r * 66 + lcol + 0] = __float2bfloat16(v.x);
    tile[r * 66 + lcol + 1] = __float2bfloat16(v.y);
    tile[r * 66 + lcol + 2] = __float2bfloat16(v.z);
    tile[r * 66 + lcol + 3] = __float2bfloat16(v.w);
  }
  __syncthreads();
  int orow_l = tid >> 3, ocol = (tid & 7) * 8;
#pragma unroll
  for (int p = 0; p < 2; p++) {
    int orow = p * 32 + orow_l;  // output row == original column
    union { __hip_bfloat16 h[8]; uint4 u; } pk;
#pragma unroll
    for (int j = 0; j < 8; j++) pk.h[j] = tile[(ocol + j) * 66 + orow];
    *(uint4*)(op + (size_t)orow * Rr + ocol) = pk.u;
  }
}

// ---------------- router: logits -> top2 -> gates + slot assignment ----------------
__global__ __launch_bounds__(256) void router_kernel(const float* __restrict__ x,
                                                     const float* __restrict__ rw,
                                                     int* __restrict__ counts,
                                                     int* __restrict__ pair_e,
                                                     int* __restrict__ pair_slot,
                                                     float* __restrict__ pair_gate) {
  int lane = threadIdx.x & 63;
  int wid = threadIdx.x >> 6;
  int t = blockIdx.x * 4 + wid;  // one wave per token
  const float* xr = x + (size_t)t * DDIM;
  float acc[NEXP];
#pragma unroll
  for (int e = 0; e < NEXP; e++) acc[e] = 0.f;
  for (int d0 = lane * 4; d0 < DDIM; d0 += 256) {
    float4 xv = *(const float4*)(xr + d0);
    const float* r0 = rw + (size_t)d0 * NEXP;
#pragma unroll
    for (int e = 0; e < NEXP; e++)
      acc[e] += xv.x * r0[e] + xv.y * r0[NEXP + e] + xv.z * r0[2 * NEXP + e] + xv.w * r0[3 * NEXP + e];
  }
#pragma unroll
  for (int e = 0; e < NEXP; e++) {
#pragma unroll
    for (int m = 32; m > 0; m >>= 1) acc[e] += __shfl_xor(acc[e], m, 64);
  }
  if (lane == 0) {
    int e1 = 0; float l1 = acc[0];
    for (int e = 1; e < NEXP; e++) if (acc[e] > l1) { l1 = acc[e]; e1 = e; }
    int e2 = -1; float l2 = -1e30f;
    for (int e = 0; e < NEXP; e++) { if (e == e1) continue; if (acc[e] > l2) { l2 = acc[e]; e2 = e; } }
    // renormalized top-2 softmax == softmax over the two logits
    float g1 = 1.f / (1.f + __expf(l2 - l1));
    float g2 = 1.f - g1;
    int s1 = atomicAdd(&counts[e1], 1);
    int s2 = atomicAdd(&counts[e2], 1);
    pair_e[2 * t] = e1;     pair_slot[2 * t] = s1;     pair_gate[2 * t] = g1;
    pair_e[2 * t + 1] = e2; pair_slot[2 * t + 1] = s2; pair_gate[2 * t + 1] = g2;
  }
}

// ---------------- gather: x rows -> expert-compacted bf16 Xg ----------------
__global__ __launch_bounds__(256) void gather_kernel(const float* __restrict__ x,
                                                     const int* __restrict__ counts,
                                                     const int* __restrict__ pair_e,
                                                     const int* __restrict__ pair_slot,
                                                     const float* __restrict__ pair_gate,
                                                     __hip_bfloat16* __restrict__ Xg,
                                                     int* __restrict__ trow,
                                                     float* __restrict__ row_gate) {
  int p = blockIdx.x;
  int t = p >> 1;
  int e = pair_e[p];
  int base = 0;
#pragma unroll
  for (int i = 0; i < NEXP; i++) base += (i < e) ? counts[i] : 0;
  int row = base + pair_slot[p];
  const float* xr = x + (size_t)t * DDIM;
  __hip_bfloat16* dst = Xg + (size_t)row * DDIM;
  int i = threadIdx.x * 4;
  float4 v = *(const float4*)(xr + i);
  union { ushort4 u; __hip_bfloat16 h[4]; } o;
  o.h[0] = __float2bfloat16(v.x);
  o.h[1] = __float2bfloat16(v.y);
  o.h[2] = __float2bfloat16(v.z);
  o.h[3] = __float2bfloat16(v.w);
  *(ushort4*)(dst + i) = o.u;
  if (threadIdx.x == 0) { trow[p] = row; row_gate[row] = pair_gate[p]; }
}

// ---------------- 256x256 8-phase bf16 MFMA GEMM, per-expert row ranges ----------------
// A: bf16 [RPAD][K] (expert-compacted). Bw: bf16 [E][N][K].
// LDS 128 KiB dynamic: A/B x 2 buffers x 2 K-halves; slot = 256 rows x 32 k (16 KiB).
// Chunk swizzle (involution, applied to global SOURCE and fragment READ; LDS write linear):
//   slot chunk s of row r holds global chunk s ^ ((r>>1)&3) -> ds_read_b128 spreads a
//   wave's 64 lanes over all 32 bank-granules exactly 2x (2-way aliasing == free, m136).
// Schedule (derived, race-free): iteration = K-tiles (2i,2i+1); phases 0-3 compute buf0,
//   4-7 compute buf1; phase p issues exactly the half-tile whose slot was last read in
//   phase p-1 (WAR protected by phase-(p-1) end barrier); vmcnt(4) only at phases 3 and 7
//   retires the buffer the next 4 phases read while keeping the next half-tile in flight.
//   EPI=0: Hout = gelu(A@B) bf16.  EPI=1: Cout = gate*(A@B) fp32.

#define MF(MM, NN, AV, BV) \
  acc[MM][NN] = __builtin_amdgcn_mfma_f32_16x16x32_bf16(AV, BV, acc[MM][NN], 0, 0, 0)

#define STAGE_A(t, kh) do {                                                     \
    __hip_bfloat16* l_ = lds + ((((t) & 1) * 2 + (kh)) * 8192);                 \
    const __hip_bfloat16* g_ = Abase + (size_t)(t) * BK + (kh) * 32;            \
    GLOBAL_TO_LDS16(g_ + sOff0, l_ + ldst0);                                    \
    GLOBAL_TO_LDS16(g_ + sOff1, l_ + ldst1);                                    \
  } while (0)

#define STAGE_B(t, kh) do {                                                     \
    __hip_bfloat16* l_ = lds + 32768 + ((((t) & 1) * 2 + (kh)) * 8192);         \
    const __hip_bfloat16* g_ = Bbase + (size_t)(t) * BK + (kh) * 32;            \
    GLOBAL_TO_LDS16(g_ + sOff0, l_ + ldst0);                                    \
    GLOBAL_TO_LDS16(g_ + sOff1, l_ + ldst1);                                    \
  } while (0)

#define PHASE(T, KH, MH, ISSUE, ...) do {                                       \
    const __hip_bfloat16* As_ = lds + (((T) * 2 + (KH)) * 8192);                \
    const __hip_bfloat16* Bs_ = lds + 32768 + (((T) * 2 + (KH)) * 8192);        \
    bf16x8 a0_ = *(const bf16x8*)(As_ + offA[(MH) * 4 + 0]);                    \
    bf16x8 a1_ = *(const bf16x8*)(As_ + offA[(MH) * 4 + 1]);                    \
    bf16x8 a2_ = *(const bf16x8*)(As_ + offA[(MH) * 4 + 2]);                    \
    bf16x8 a3_ = *(const bf16x8*)(As_ + offA[(MH) * 4 + 3]);                    \
    if ((MH) == 0) {                                                            \
      vb0 = *(const bf16x8*)(Bs_ + offB[0]);                                    \
      vb1 = *(const bf16x8*)(Bs_ + offB[1]);                                    \
      vb2 = *(const bf16x8*)(Bs_ + offB[2]);                                    \
      vb3 = *(const bf16x8*)(Bs_ + offB[3]);                                    \
    }                                                                           \
    ISSUE;                                                                      \
    __VA_ARGS__;                                                                \
    __builtin_amdgcn_s_barrier();                                               \
    asm volatile("s_waitcnt lgkmcnt(0)" ::: "memory");                          \
    __builtin_amdgcn_sched_barrier(0);                                          \
    __builtin_amdgcn_s_setprio(1);                                              \
    MF((MH)*4+0, 0, a0_, vb0); MF((MH)*4+0, 1, a0_, vb1);                       \
    MF((MH)*4+0, 2, a0_, vb2); MF((MH)*4+0, 3, a0_, vb3);                       \
    MF((MH)*4+1, 0, a1_, vb0); MF((MH)*4+1, 1, a1_, vb1);                       \
    MF((MH)*4+1, 2, a1_, vb2); MF((MH)*4+1, 3, a1_, vb3);                       \
    MF((MH)*4+2, 0, a2_, vb0); MF((MH)*4+2, 1, a2_, vb1);                       \
    MF((MH)*4+2, 2, a2_, vb2); MF((MH)*4+2, 3, a2_, vb3);                       \
    MF((MH)*4+3, 0, a3_, vb0); MF((MH)*4+3, 1, a3_, vb1);                       \
    MF((MH)*4+3, 2, a3_, vb2); MF((MH)*4+3, 3, a3_, vb3);                       \
    __builtin_amdgcn_s_setprio(0);                                              \
    __builtin_amdgcn_sched_barrier(0);                                          \
    __builtin_amdgcn_s_barrier();                                               \
  } while (0)

template <int EPI>
__global__ __launch_bounds__(512, 2) void moe_gemm8(const __hip_bfloat16* __restrict__ A,
                                                    const __hip_bfloat16* __restrict__ Bw,
                                                    __hip_bfloat16* __restrict__ Hout,
                                                    float* __restrict__ Cout,
                                                    const int* __restrict__ counts,
                                                    const float* __restrict__ row_gate,
                                                    int K, int N) {
  extern __shared__ __align__(16) __hip_bfloat16 lds[];
  const int MT = T_TOK / BM;  // 32 worst-case m-tiles per expert
  const int NT = N / BN;

  // bijective XCD swizzle (m204 form; grids here are multiples of 8)
  int nwg = gridDim.x;
  int bid0 = blockIdx.x;
  int xcd = bid0 & 7, idx = bid0 >> 3;
  int qq = nwg >> 3, rr8 = nwg & 7;
  int wg = (xcd < rr8 ? xcd * (qq + 1) : rr8 * (qq + 1) + (xcd - rr8) * qq) + idx;

  int e = wg / (MT * NT);
  int rem = wg % (MT * NT);
  const int GM = 8;
  int width = GM * NT;
  int group = rem / width;
  int gm0 = group * GM;
  int gsize = (MT - gm0 < GM) ? (MT - gm0) : GM;
  int mt = gm0 + (rem % gsize);
  int nt = (rem % width) / gsize;

  int n_e = counts[e];
  if (mt * BM >= n_e) return;
  int row0 = 0;
#pragma unroll
  for (int i = 0; i < NEXP; i++) row0 += (i < e) ? counts[i] : 0;
  int m_start = row0 + mt * BM;
  int row_end = row0 + n_e;

  const __hip_bfloat16* Abase = A + (size_t)m_start * K;
  const __hip_bfloat16* Bbase = Bw + (size_t)e * N * K + (size_t)(nt * BN) * K;

  int tid = threadIdx.x;
  int lane = tid & 63, wid = tid >> 6;
  int wm = (wid >> 2) * 128, wn = (wid & 3) * 64;  // 2x4 wave grid, 128x64 each
  int lr = lane & 15, lc = lane >> 4;

  // staging thread pattern: 2 x global_load_lds(16B) per half-tile; source pre-swizzled
  int q0 = tid, q1 = 512 + tid;
  int r0 = q0 >> 2, c0 = (q0 & 3) ^ ((r0 >> 1) & 3);
  int r1 = q1 >> 2, c1 = (q1 & 3) ^ ((r1 >> 1) & 3);
  size_t sOff0 = (size_t)r0 * K + c0 * 8;
  size_t sOff1 = (size_t)r1 * K + c1 * 8;
  int ldst0 = (q0 & ~63) * 8;   // wave-uniform LDS dst (elements)
  int ldst1 = (q1 & ~63) * 8;

  // fragment read offsets within a slot (same swizzle involution)
  int offA[8], offB[4];
#pragma unroll
  for (int m = 0; m < 8; m++) { int R = wm + m * 16 + lr; offA[m] = R * 32 + ((lc ^ ((R >> 1) & 3)) << 3); }
#pragma unroll
  for (int n = 0; n < 4; n++) { int R = wn + n * 16 + lr; offB[n] = R * 32 + ((lc ^ ((R >> 1) & 3)) << 3); }

  f32x4 acc[8][4];
#pragma unroll
  for (int m = 0; m < 8; m++)
#pragma unroll
    for (int n = 0; n < 4; n++)
#pragma unroll
      for (int r = 0; r < 4; r++) acc[m][n][r] = 0.f;
  bf16x8 vb0 = {}, vb1 = {}, vb2 = {}, vb3 = {};

  // prologue: K-tile 0 fully, K-tile 1 half0; vmcnt(4) leaves K1.h0 in flight
  STAGE_A(0, 0); STAGE_B(0, 0);
  STAGE_A(0, 1); STAGE_B(0, 1);
  STAGE_A(1, 0); STAGE_B(1, 0);
  asm volatile("s_waitcnt vmcnt(4)" ::: "memory");
  __builtin_amdgcn_s_barrier();

  int NIT = K / (2 * BK);  // >= 2 and even K-tile count for both GEMMs
  for (int it = 0; it < NIT - 1; ++it) {
    int t1 = 2 * it + 1;
    PHASE(0, 0, 0, STAGE_A(t1, 1));
    PHASE(0, 0, 1, STAGE_B(t1, 1));
    PHASE(0, 1, 0, STAGE_A(t1 + 1, 0));
    PHASE(0, 1, 1, STAGE_B(t1 + 1, 0), asm volatile("s_waitcnt vmcnt(4)" ::: "memory"));
    PHASE(1, 0, 0, STAGE_A(t1 + 1, 1));
    PHASE(1, 0, 1, STAGE_B(t1 + 1, 1));
    PHASE(1, 1, 0, STAGE_A(t1 + 2, 0));
    PHASE(1, 1, 1, STAGE_B(t1 + 2, 0), asm volatile("s_waitcnt vmcnt(4)" ::: "memory"));
  }
  {  // final iteration: only the last K-tile's second half remains to stage
    int t1 = K / BK - 1;
    PHASE(0, 0, 0, STAGE_A(t1, 1));
    PHASE(0, 0, 1, STAGE_B(t1, 1));
    PHASE(0, 1, 0, ((void)0));
    PHASE(0, 1, 1, ((void)0), asm volatile("s_waitcnt vmcnt(0)" ::: "memory"));
    PHASE(1, 0, 0, ((void)0));
    PHASE(1, 0, 1, ((void)0));
    PHASE(1, 1, 0, ((void)0));
    PHASE(1, 1, 1, ((void)0));
  }

  // epilogue; C/D layout: col = lane&15, row = (lane>>4)*4 + reg  [m89-verified]
  int quad = lc * 4;
#pragma unroll
  for (int m = 0; m < 8; m++) {
#pragma unroll
    for (int r = 0; r < 4; r++) {
      int grow = m_start + wm + m * 16 + quad + r;
      if (grow < row_end) {
        size_t basei = (size_t)grow * N + nt * BN + wn + lr;
        if (EPI == 0) {
#pragma unroll
          for (int n = 0; n < 4; n++)
            Hout[basei + n * 16] = __float2bfloat16(gelu_tanh(acc[m][n][r]));
        } else {
          float g = row_gate[grow];
#pragma unroll
          for (int n = 0; n < 4; n++)
            Cout[basei + n * 16] = g * acc[m][n][r];
        }
      }
    }
  }
}

// ---------------- combine: out[t] = P[row1] + P[row2] (gates pre-applied) ----------------
__global__ __launch_bounds__(256) void combine_kernel(const float* __restrict__ P,
                                                      const int* __restrict__ trow,
                                                      float* __restrict__ out) {
  int t = blockIdx.x;
  int r1 = trow[2 * t], r2 = trow[2 * t + 1];
  int d = threadIdx.x * 4;
  float4 a = *(const float4*)(P + (size_t)r1 * DDIM + d);
  float4 b = *(const float4*)(P + (size_t)r2 * DDIM + d);
  float4 o;
  o.x = a.x + b.x; o.y = a.y + b.y; o.z = a.z + b.z; o.w = a.w + b.w;
  *(float4*)(out + (size_t)t * DDIM + d) = o;
}

extern "C" void kernel_launch(void* const* d_in, const int* in_sizes, int n_in,
                              void* d_out, int out_size, void* d_ws, size_t ws_size,
                              hipStream_t stream) {
  (void)in_sizes; (void)n_in; (void)out_size; (void)ws_size;
  const float* x  = (const float*)d_in[0];
  const float* rw = (const float*)d_in[1];
  const float* w1 = (const float*)d_in[2];
  const float* w2 = (const float*)d_in[3];
  float* out = (float*)d_out;

  char* ws = (char*)d_ws;
  size_t off = 0;
  auto alloc = [&](size_t bytes) -> char* {
    off = (off + 255) & ~(size_t)255;
    char* p = ws + off;
    off += bytes;
    return p;
  };
  int*   counts    = (int*)alloc(NEXP * 4);
  int*   pair_e    = (int*)alloc((size_t)RTOT * 4);
  int*   pair_slot = (int*)alloc((size_t)RTOT * 4);
  float* pair_gate = (float*)alloc((size_t)RTOT * 4);
  int*   trow      = (int*)alloc((size_t)RTOT * 4);
  float* row_gate  = (float*)alloc((size_t)RTOT * 4);
  __hip_bfloat16* Xg  = (__hip_bfloat16*)alloc((size_t)RPAD * DDIM * 2);
  __hip_bfloat16* w1t = (__hip_bfloat16*)alloc((size_t)NEXP * DDIM * FDIM * 2);
  __hip_bfloat16* w2t = (__hip_bfloat16*)alloc((size_t)NEXP * DDIM * FDIM * 2);
  __hip_bfloat16* H   = (__hip_bfloat16*)alloc((size_t)RPAD * FDIM * 2);
  // P aliases w1t: w1t is dead after GEMM1; both are 64+ MB. Every call rewrites
  // w1t (transpose) before GEMM1, and GEMM2 fully writes P before combine reads it.
  float* P = (float*)w1t;      // [RTOT][DDIM] fp32 gated partials

  // host-side attribute set; graph-capture-safe, cheap -> do it every call
  hipFuncSetAttribute(reinterpret_cast<const void*>(moe_gemm8<0>),
                      hipFuncAttributeMaxDynamicSharedMemorySize, 131072);
  hipFuncSetAttribute(reinterpret_cast<const void*>(moe_gemm8<1>),
                      hipFuncAttributeMaxDynamicSharedMemorySize, 131072);

  hipMemsetAsync(counts, 0, NEXP * 4, stream);

  transpose_cast_both<<<2 * NEXP * 1024, 256, 0, stream>>>(w1, w2, w1t, w2t);
  router_kernel<<<T_TOK / 4, 256, 0, stream>>>(x, rw, counts, pair_e, pair_slot, pair_gate);
  gather_kernel<<<RTOT, 256, 0, stream>>>(x, counts, pair_e, pair_slot, pair_gate, Xg, trow, row_gate);

  moe_gemm8<0><<<NEXP * (T_TOK / BM) * (FDIM / BN), 512, 131072, stream>>>(
      Xg, w1t, H, nullptr, counts, nullptr, DDIM, FDIM);
  moe_gemm8<1><<<NEXP * (T_TOK / BM) * (DDIM / BN), 512, 131072, stream>>>(
      H, w2t, nullptr, P, counts, row_gate, FDIM, DDIM);
  combine_kernel<<<T_TOK, 256, 0, stream>>>(P, trow, out);
}

// Round 3
// 985.212 us; speedup vs baseline: 1.0132x; 1.0132x over previous
//
#include <hip/hip_runtime.h>
#include <hip/hip_bf16.h>

// MoE top-2: T=8192 tokens, D=1024, F=4096, E=8.
// Pipeline: fused transpose-cast -> router -> gather -> GEMM1(gelu) -> GEMM2(gated P) -> combine.
// GEMMs: 256x256 8-phase schedule (T1 XCD-swizzle + T2 LDS swizzle + T3/T4 counted-vmcnt + T5 setprio).
// R2 fix: per-half-K vmcnt(8) waits at phases 1/3/5/7 (was vmcnt(4) at 3/7). FIFO forced the
// old wait to retire loads issued only 2 phases earlier (~560cyc < 900cyc HBM) -> 340cyc stall
// per 4 phases == measured MfmaUtil 26%. New waits give every half-tile a 4-5 phase lead.

#define T_TOK 8192
#define DDIM  1024
#define FDIM  4096
#define NEXP  8
#define RTOT  (T_TOK * 2)      // total assigned rows (top-2, always exactly 2T)
#define RPAD  (RTOT + 256)     // slack so 256-row tile staging can over-read harmlessly

#define BM 256
#define BN 256
#define BK 64

typedef __bf16 bf16x8 __attribute__((ext_vector_type(8)));
typedef float  f32x4  __attribute__((ext_vector_type(4)));

__device__ __forceinline__ float gelu_tanh(float x) {
  // 0.5x(1+tanh(u)) == x * sigmoid(2u); u = sqrt(2/pi)(x + 0.044715 x^3)
  float u = 0.7978845608028654f * (x + 0.044715f * x * x * x);
  return __fdividef(x, 1.f + __expf(-2.f * u));
}

#define GLOBAL_TO_LDS16(gp, lp)                                                   \
  __builtin_amdgcn_global_load_lds((const __attribute__((address_space(1))) void*)(gp), \
                                   (__attribute__((address_space(3))) void*)(lp), 16, 0, 0)

// ---------------- fused transpose+cast for w1 and w2 ----------------
// fp32 [E][Rr][Cc] -> bf16 [E][Cc][Rr]. float4 loads, 16B bf16 stores.
__global__ __launch_bounds__(256) void transpose_cast_both(const float* __restrict__ w1,
                                                           const float* __restrict__ w2,
                                                           __hip_bfloat16* __restrict__ w1t,
                                                           __hip_bfloat16* __restrict__ w2t) {
  __shared__ __hip_bfloat16 tile[64 * 66];
  int bid = blockIdx.x;
  const float* in; __hip_bfloat16* outp; int Rr, Cc;
  if (bid < NEXP * 1024) { in = w1; outp = w1t; Rr = DDIM; Cc = FDIM; }
  else { bid -= NEXP * 1024; in = w2; outp = w2t; Rr = FDIM; Cc = DDIM; }
  int tilesC = Cc >> 6;
  int per = (Rr >> 6) * tilesC;  // == 1024
  int e = bid / per, rem = bid % per;
  int tr = rem / tilesC, tc = rem % tilesC;
  const float* ip = in + (size_t)e * Rr * Cc + (size_t)(tr * 64) * Cc + tc * 64;
  __hip_bfloat16* op = outp + (size_t)e * Rr * Cc + (size_t)(tc * 64) * Rr + tr * 64;
  int tid = threadIdx.x;
  int lrow = tid >> 4, lcol = (tid & 15) * 4;
#pragma unroll
  for (int p = 0; p < 4; p++) {
    int r = p * 16 + lrow;
    float4 v = *(const float4*)(ip + (size_t)r * Cc + lcol);
    tile[r * 66 + lcol + 0] = __float2bfloat16(v.x);
    tile[r * 66 + lcol + 1] = __float2bfloat16(v.y);
    tile[r * 66 + lcol + 2] = __float2bfloat16(v.z);
    tile[r * 66 + lcol + 3] = __float2bfloat16(v.w);
  }
  __syncthreads();
  int orow_l = tid >> 3, ocol = (tid & 7) * 8;
#pragma unroll
  for (int p = 0; p < 2; p++) {
    int orow = p * 32 + orow_l;  // output row == original column
    union { __hip_bfloat16 h[8]; uint4 u; } pk;
#pragma unroll
    for (int j = 0; j < 8; j++) pk.h[j] = tile[(ocol + j) * 66 + orow];
    *(uint4*)(op + (size_t)orow * Rr + ocol) = pk.u;
  }
}

// ---------------- router: logits -> top2 -> gates + slot assignment ----------------
__global__ __launch_bounds__(256) void router_kernel(const float* __restrict__ x,
                                                     const float* __restrict__ rw,
                                                     int* __restrict__ counts,
                                                     int* __restrict__ pair_e,
                                                     int* __restrict__ pair_slot,
                                                     float* __restrict__ pair_gate) {
  int lane = threadIdx.x & 63;
  int wid = threadIdx.x >> 6;
  int t = blockIdx.x * 4 + wid;  // one wave per token
  const float* xr = x + (size_t)t * DDIM;
  float acc[NEXP];
#pragma unroll
  for (int e = 0; e < NEXP; e++) acc[e] = 0.f;
  for (int d0 = lane * 4; d0 < DDIM; d0 += 256) {
    float4 xv = *(const float4*)(xr + d0);
    const float* r0 = rw + (size_t)d0 * NEXP;
#pragma unroll
    for (int e = 0; e < NEXP; e++)
      acc[e] += xv.x * r0[e] + xv.y * r0[NEXP + e] + xv.z * r0[2 * NEXP + e] + xv.w * r0[3 * NEXP + e];
  }
#pragma unroll
  for (int e = 0; e < NEXP; e++) {
#pragma unroll
    for (int m = 32; m > 0; m >>= 1) acc[e] += __shfl_xor(acc[e], m, 64);
  }
  if (lane == 0) {
    int e1 = 0; float l1 = acc[0];
    for (int e = 1; e < NEXP; e++) if (acc[e] > l1) { l1 = acc[e]; e1 = e; }
    int e2 = -1; float l2 = -1e30f;
    for (int e = 0; e < NEXP; e++) { if (e == e1) continue; if (acc[e] > l2) { l2 = acc[e]; e2 = e; } }
    // renormalized top-2 softmax == softmax over the two logits
    float g1 = 1.f / (1.f + __expf(l2 - l1));
    float g2 = 1.f - g1;
    int s1 = atomicAdd(&counts[e1], 1);
    int s2 = atomicAdd(&counts[e2], 1);
    pair_e[2 * t] = e1;     pair_slot[2 * t] = s1;     pair_gate[2 * t] = g1;
    pair_e[2 * t + 1] = e2; pair_slot[2 * t + 1] = s2; pair_gate[2 * t + 1] = g2;
  }
}

// ---------------- gather: x rows -> expert-compacted bf16 Xg ----------------
__global__ __launch_bounds__(256) void gather_kernel(const float* __restrict__ x,
                                                     const int* __restrict__ counts,
                                                     const int* __restrict__ pair_e,
                                                     const int* __restrict__ pair_slot,
                                                     const float* __restrict__ pair_gate,
                                                     __hip_bfloat16* __restrict__ Xg,
                                                     int* __restrict__ trow,
                                                     float* __restrict__ row_gate) {
  int p = blockIdx.x;
  int t = p >> 1;
  int e = pair_e[p];
  int base = 0;
#pragma unroll
  for (int i = 0; i < NEXP; i++) base += (i < e) ? counts[i] : 0;
  int row = base + pair_slot[p];
  const float* xr = x + (size_t)t * DDIM;
  __hip_bfloat16* dst = Xg + (size_t)row * DDIM;
  int i = threadIdx.x * 4;
  float4 v = *(const float4*)(xr + i);
  union { ushort4 u; __hip_bfloat16 h[4]; } o;
  o.h[0] = __float2bfloat16(v.x);
  o.h[1] = __float2bfloat16(v.y);
  o.h[2] = __float2bfloat16(v.z);
  o.h[3] = __float2bfloat16(v.w);
  *(ushort4*)(dst + i) = o.u;
  if (threadIdx.x == 0) { trow[p] = row; row_gate[row] = pair_gate[p]; }
}

// ---------------- 256x256 8-phase bf16 MFMA GEMM, per-expert row ranges ----------------
// A: bf16 [RPAD][K] (expert-compacted). Bw: bf16 [E][N][K].
// LDS 128 KiB dynamic: A/B x 2 buffers x 2 K-halves; slot = 256 rows x 32 k (16 KiB).
// Chunk swizzle (involution, applied to global SOURCE and fragment READ; LDS write linear).
// Schedule ledger (steady state; iteration computes tiles 2i (buf0), 2i+1 (buf1); 2 load
// instr per STAGE):
//   entry invariant: tile2i.kh0 resident; 8 outstanding = {tile2i.kh1, tile(2i+1).kh0}
//   ph0 read b0.kh0            stage (2i+1).kh1.A  -> 10
//   ph1 read b0.kh0            stage (2i+1).kh1.B  -> 12, vmcnt(8): retire tile2i.kh1
//   ph2 read b0.kh1            stage (2i+2).kh0.A  -> 10
//   ph3 read b0.kh1            stage (2i+2).kh0.B  -> 12, vmcnt(8): retire (2i+1).kh0
//   ph4 read b1.kh0            stage (2i+2).kh1.A  -> 10
//   ph5 read b1.kh0            stage (2i+2).kh1.B  -> 12, vmcnt(8): retire (2i+1).kh1
//   ph6 read b1.kh1            stage (2i+3).kh0.A  -> 10
//   ph7 read b1.kh1            stage (2i+3).kh0.B  -> 12, vmcnt(8): retire (2i+2).kh0
// Every half-tile has a 4-5 phase issue-to-retire lead (covers ~900cyc HBM latency).
//   EPI=0: Hout = gelu(A@B) bf16.  EPI=1: Cout = gate*(A@B) fp32.

#define MF(MM, NN, AV, BV) \
  acc[MM][NN] = __builtin_amdgcn_mfma_f32_16x16x32_bf16(AV, BV, acc[MM][NN], 0, 0, 0)

#define STAGE_A(t, kh) do {                                                     \
    __hip_bfloat16* l_ = lds + ((((t) & 1) * 2 + (kh)) * 8192);                 \
    const __hip_bfloat16* g_ = Abase + (size_t)(t) * BK + (kh) * 32;            \
    GLOBAL_TO_LDS16(g_ + sOff0, l_ + ldst0);                                    \
    GLOBAL_TO_LDS16(g_ + sOff1, l_ + ldst1);                                    \
  } while (0)

#define STAGE_B(t, kh) do {                                                     \
    __hip_bfloat16* l_ = lds + 32768 + ((((t) & 1) * 2 + (kh)) * 8192);         \
    const __hip_bfloat16* g_ = Bbase + (size_t)(t) * BK + (kh) * 32;            \
    GLOBAL_TO_LDS16(g_ + sOff0, l_ + ldst0);                                    \
    GLOBAL_TO_LDS16(g_ + sOff1, l_ + ldst1);                                    \
  } while (0)

#define PHASE(T, KH, MH, ISSUE, ...) do {                                       \
    const __hip_bfloat16* As_ = lds + (((T) * 2 + (KH)) * 8192);                \
    const __hip_bfloat16* Bs_ = lds + 32768 + (((T) * 2 + (KH)) * 8192);        \
    bf16x8 a0_ = *(const bf16x8*)(As_ + offA[(MH) * 4 + 0]);                    \
    bf16x8 a1_ = *(const bf16x8*)(As_ + offA[(MH) * 4 + 1]);                    \
    bf16x8 a2_ = *(const bf16x8*)(As_ + offA[(MH) * 4 + 2]);                    \
    bf16x8 a3_ = *(const bf16x8*)(As_ + offA[(MH) * 4 + 3]);                    \
    if ((MH) == 0) {                                                            \
      vb0 = *(const bf16x8*)(Bs_ + offB[0]);                                    \
      vb1 = *(const bf16x8*)(Bs_ + offB[1]);                                    \
      vb2 = *(const bf16x8*)(Bs_ + offB[2]);                                    \
      vb3 = *(const bf16x8*)(Bs_ + offB[3]);                                    \
    }                                                                           \
    ISSUE;                                                                      \
    __VA_ARGS__;                                                                \
    __builtin_amdgcn_s_barrier();                                               \
    asm volatile("s_waitcnt lgkmcnt(0)" ::: "memory");                          \
    __builtin_amdgcn_sched_barrier(0);                                          \
    __builtin_amdgcn_s_setprio(1);                                              \
    MF((MH)*4+0, 0, a0_, vb0); MF((MH)*4+0, 1, a0_, vb1);                       \
    MF((MH)*4+0, 2, a0_, vb2); MF((MH)*4+0, 3, a0_, vb3);                       \
    MF((MH)*4+1, 0, a1_, vb0); MF((MH)*4+1, 1, a1_, vb1);                       \
    MF((MH)*4+1, 2, a1_, vb2); MF((MH)*4+1, 3, a1_, vb3);                       \
    MF((MH)*4+2, 0, a2_, vb0); MF((MH)*4+2, 1, a2_, vb1);                       \
    MF((MH)*4+2, 2, a2_, vb2); MF((MH)*4+2, 3, a2_, vb3);                       \
    MF((MH)*4+3, 0, a3_, vb0); MF((MH)*4+3, 1, a3_, vb1);                       \
    MF((MH)*4+3, 2, a3_, vb2); MF((MH)*4+3, 3, a3_, vb3);                       \
    __builtin_amdgcn_s_setprio(0);                                              \
    __builtin_amdgcn_sched_barrier(0);                                          \
    __builtin_amdgcn_s_barrier();                                               \
  } while (0)

template <int EPI>
__global__ __launch_bounds__(512, 2) void moe_gemm8(const __hip_bfloat16* __restrict__ A,
                                                    const __hip_bfloat16* __restrict__ Bw,
                                                    __hip_bfloat16* __restrict__ Hout,
                                                    float* __restrict__ Cout,
                                                    const int* __restrict__ counts,
                                                    const float* __restrict__ row_gate,
                                                    int K, int N) {
  extern __shared__ __align__(16) __hip_bfloat16 lds[];
  const int MT = T_TOK / BM;  // 32 worst-case m-tiles per expert
  const int NT = N / BN;

  // bijective XCD swizzle (m204 form; grids here are multiples of 8)
  int nwg = gridDim.x;
  int bid0 = blockIdx.x;
  int xcd = bid0 & 7, idx = bid0 >> 3;
  int qq = nwg >> 3, rr8 = nwg & 7;
  int wg = (xcd < rr8 ? xcd * (qq + 1) : rr8 * (qq + 1) + (xcd - rr8) * qq) + idx;

  int e = wg / (MT * NT);
  int rem = wg % (MT * NT);
  const int GM = 8;
  int width = GM * NT;
  int group = rem / width;
  int gm0 = group * GM;
  int gsize = (MT - gm0 < GM) ? (MT - gm0) : GM;
  int mt = gm0 + (rem % gsize);
  int nt = (rem % width) / gsize;

  int n_e = counts[e];
  if (mt * BM >= n_e) return;
  int row0 = 0;
#pragma unroll
  for (int i = 0; i < NEXP; i++) row0 += (i < e) ? counts[i] : 0;
  int m_start = row0 + mt * BM;
  int row_end = row0 + n_e;

  const __hip_bfloat16* Abase = A + (size_t)m_start * K;
  const __hip_bfloat16* Bbase = Bw + (size_t)e * N * K + (size_t)(nt * BN) * K;

  int tid = threadIdx.x;
  int lane = tid & 63, wid = tid >> 6;
  int wm = (wid >> 2) * 128, wn = (wid & 3) * 64;  // 2x4 wave grid, 128x64 each
  int lr = lane & 15, lc = lane >> 4;

  // staging thread pattern: 2 x global_load_lds(16B) per half-tile; source pre-swizzled
  int q0 = tid, q1 = 512 + tid;
  int r0 = q0 >> 2, c0 = (q0 & 3) ^ ((r0 >> 1) & 3);
  int r1 = q1 >> 2, c1 = (q1 & 3) ^ ((r1 >> 1) & 3);
  size_t sOff0 = (size_t)r0 * K + c0 * 8;
  size_t sOff1 = (size_t)r1 * K + c1 * 8;
  int ldst0 = (q0 & ~63) * 8;   // wave-uniform LDS dst (elements)
  int ldst1 = (q1 & ~63) * 8;

  // fragment read offsets within a slot (same swizzle involution)
  int offA[8], offB[4];
#pragma unroll
  for (int m = 0; m < 8; m++) { int R = wm + m * 16 + lr; offA[m] = R * 32 + ((lc ^ ((R >> 1) & 3)) << 3); }
#pragma unroll
  for (int n = 0; n < 4; n++) { int R = wn + n * 16 + lr; offB[n] = R * 32 + ((lc ^ ((R >> 1) & 3)) << 3); }

  f32x4 acc[8][4];
#pragma unroll
  for (int m = 0; m < 8; m++)
#pragma unroll
    for (int n = 0; n < 4; n++)
#pragma unroll
      for (int r = 0; r < 4; r++) acc[m][n][r] = 0.f;
  bf16x8 vb0 = {}, vb1 = {}, vb2 = {}, vb3 = {};

  // prologue: tiles 0 (both halves) + 1.kh0 issued; vmcnt(8) -> tile0.kh0 resident,
  // 8 outstanding = {tile0.kh1, tile1.kh0} == steady-state entry invariant
  STAGE_A(0, 0); STAGE_B(0, 0);
  STAGE_A(0, 1); STAGE_B(0, 1);
  STAGE_A(1, 0); STAGE_B(1, 0);
  asm volatile("s_waitcnt vmcnt(8)" ::: "memory");
  __builtin_amdgcn_s_barrier();

  int NIT = K / (2 * BK);  // >= 2 and even K-tile count for both GEMMs
  for (int it = 0; it < NIT - 1; ++it) {
    int t1 = 2 * it + 1;
    PHASE(0, 0, 0, STAGE_A(t1, 1));
    PHASE(0, 0, 1, STAGE_B(t1, 1), asm volatile("s_waitcnt vmcnt(8)" ::: "memory"));
    PHASE(0, 1, 0, STAGE_A(t1 + 1, 0));
    PHASE(0, 1, 1, STAGE_B(t1 + 1, 0), asm volatile("s_waitcnt vmcnt(8)" ::: "memory"));
    PHASE(1, 0, 0, STAGE_A(t1 + 1, 1));
    PHASE(1, 0, 1, STAGE_B(t1 + 1, 1), asm volatile("s_waitcnt vmcnt(8)" ::: "memory"));
    PHASE(1, 1, 0, STAGE_A(t1 + 2, 0));
    PHASE(1, 1, 1, STAGE_B(t1 + 2, 0), asm volatile("s_waitcnt vmcnt(8)" ::: "memory"));
  }
  {  // final iteration: only the last K-tile's second half remains to stage.
    // entry: 8 outstanding {tile(2i).kh1, tile(2i+1).kh0}; ph0/1 add tile(2i+1).kh1.
    int t1 = K / BK - 1;
    PHASE(0, 0, 0, STAGE_A(t1, 1));
    PHASE(0, 0, 1, STAGE_B(t1, 1), asm volatile("s_waitcnt vmcnt(8)" ::: "memory"));
    PHASE(0, 1, 0, ((void)0));
    PHASE(0, 1, 1, ((void)0), asm volatile("s_waitcnt vmcnt(4)" ::: "memory"));
    PHASE(1, 0, 0, ((void)0));
    PHASE(1, 0, 1, ((void)0), asm volatile("s_waitcnt vmcnt(0)" ::: "memory"));
    PHASE(1, 1, 0, ((void)0));
    PHASE(1, 1, 1, ((void)0));
  }

  // epilogue; C/D layout: col = lane&15, row = (lane>>4)*4 + reg  [m89-verified]
  int quad = lc * 4;
#pragma unroll
  for (int m = 0; m < 8; m++) {
#pragma unroll
    for (int r = 0; r < 4; r++) {
      int grow = m_start + wm + m * 16 + quad + r;
      if (grow < row_end) {
        size_t basei = (size_t)grow * N + nt * BN + wn + lr;
        if (EPI == 0) {
#pragma unroll
          for (int n = 0; n < 4; n++)
            Hout[basei + n * 16] = __float2bfloat16(gelu_tanh(acc[m][n][r]));
        } else {
          float g = row_gate[grow];
#pragma unroll
          for (int n = 0; n < 4; n++)
            Cout[basei + n * 16] = g * acc[m][n][r];
        }
      }
    }
  }
}

// ---------------- combine: out[t] = P[row1] + P[row2] (gates pre-applied) ----------------
__global__ __launch_bounds__(256) void combine_kernel(const float* __restrict__ P,
                                                      const int* __restrict__ trow,
                                                      float* __restrict__ out) {
  int t = blockIdx.x;
  int r1 = trow[2 * t], r2 = trow[2 * t + 1];
  int d = threadIdx.x * 4;
  float4 a = *(const float4*)(P + (size_t)r1 * DDIM + d);
  float4 b = *(const float4*)(P + (size_t)r2 * DDIM + d);
  float4 o;
  o.x = a.x + b.x; o.y = a.y + b.y; o.z = a.z + b.z; o.w = a.w + b.w;
  *(float4*)(out + (size_t)t * DDIM + d) = o;
}

extern "C" void kernel_launch(void* const* d_in, const int* in_sizes, int n_in,
                              void* d_out, int out_size, void* d_ws, size_t ws_size,
                              hipStream_t stream) {
  (void)in_sizes; (void)n_in; (void)out_size; (void)ws_size;
  const float* x  = (const float*)d_in[0];
  const float* rw = (const float*)d_in[1];
  const float* w1 = (const float*)d_in[2];
  const float* w2 = (const float*)d_in[3];
  float* out = (float*)d_out;

  char* ws = (char*)d_ws;
  size_t off = 0;
  auto alloc = [&](size_t bytes) -> char* {
    off = (off + 255) & ~(size_t)255;
    char* p = ws + off;
    off += bytes;
    return p;
  };
  int*   counts    = (int*)alloc(NEXP * 4);
  int*   pair_e    = (int*)alloc((size_t)RTOT * 4);
  int*   pair_slot = (int*)alloc((size_t)RTOT * 4);
  float* pair_gate = (float*)alloc((size_t)RTOT * 4);
  int*   trow      = (int*)alloc((size_t)RTOT * 4);
  float* row_gate  = (float*)alloc((size_t)RTOT * 4);
  __hip_bfloat16* Xg  = (__hip_bfloat16*)alloc((size_t)RPAD * DDIM * 2);
  __hip_bfloat16* w1t = (__hip_bfloat16*)alloc((size_t)NEXP * DDIM * FDIM * 2);
  __hip_bfloat16* w2t = (__hip_bfloat16*)alloc((size_t)NEXP * DDIM * FDIM * 2);
  __hip_bfloat16* H   = (__hip_bfloat16*)alloc((size_t)RPAD * FDIM * 2);
  // P aliases w1t: w1t is dead after GEMM1; both are 64+ MB. Every call rewrites
  // w1t (transpose) before GEMM1, and GEMM2 fully writes P before combine reads it.
  float* P = (float*)w1t;      // [RTOT][DDIM] fp32 gated partials

  // host-side attribute set; graph-capture-safe, cheap -> do it every call
  hipFuncSetAttribute(reinterpret_cast<const void*>(moe_gemm8<0>),
                      hipFuncAttributeMaxDynamicSharedMemorySize, 131072);
  hipFuncSetAttribute(reinterpret_cast<const void*>(moe_gemm8<1>),
                      hipFuncAttributeMaxDynamicSharedMemorySize, 131072);

  hipMemsetAsync(counts, 0, NEXP * 4, stream);

  transpose_cast_both<<<2 * NEXP * 1024, 256, 0, stream>>>(w1, w2, w1t, w2t);
  router_kernel<<<T_TOK / 4, 256, 0, stream>>>(x, rw, counts, pair_e, pair_slot, pair_gate);
  gather_kernel<<<RTOT, 256, 0, stream>>>(x, counts, pair_e, pair_slot, pair_gate, Xg, trow, row_gate);

  moe_gemm8<0><<<NEXP * (T_TOK / BM) * (FDIM / BN), 512, 131072, stream>>>(
      Xg, w1t, H, nullptr, counts, nullptr, DDIM, FDIM);
  moe_gemm8<1><<<NEXP * (T_TOK / BM) * (DDIM / BN), 512, 131072, stream>>>(
      H, w2t, nullptr, P, counts, row_gate, FDIM, DDIM);
  combine_kernel<<<T_TOK, 256, 0, stream>>>(P, trow, out);
}

// Round 4
// 977.965 us; speedup vs baseline: 1.0207x; 1.0074x over previous
//
#include <hip/hip_runtime.h>
#include <hip/hip_bf16.h>

// MoE top-2: T=8192 tokens, D=1024, F=4096, E=8.
// Pipeline: fused transpose-cast -> router -> gather -> GEMM1(gelu) -> GEMM2(gated P) -> combine.
// GEMMs: 256x256 8-phase schedule (T1 XCD-swizzle + T2 LDS swizzle + T3/T4 counted-vmcnt + T5 setprio).
// R4 fix: removed per-phase asm lgkmcnt(0) + sched_barrier(0) pins. They forced a FULL LDS
// drain (~900cyc, 8 waves x 8-12 ds_reads) before the FIRST MFMA, serializing LDS and matrix
// pipes -> phase ~2250cyc vs ~620cyc MFMA floor == measured 26% MfmaUtil. Compiler-tracked
// ds_read->MFMA deps emit progressive lgkmcnt(N), overlapping the two pipes (m97 asm evidence).

#define T_TOK 8192
#define DDIM  1024
#define FDIM  4096
#define NEXP  8
#define RTOT  (T_TOK * 2)      // total assigned rows (top-2, always exactly 2T)
#define RPAD  (RTOT + 256)     // slack so 256-row tile staging can over-read harmlessly

#define BM 256
#define BN 256
#define BK 64

typedef __bf16 bf16x8 __attribute__((ext_vector_type(8)));
typedef float  f32x4  __attribute__((ext_vector_type(4)));

__device__ __forceinline__ float gelu_tanh(float x) {
  // 0.5x(1+tanh(u)) == x * sigmoid(2u); u = sqrt(2/pi)(x + 0.044715 x^3)
  float u = 0.7978845608028654f * (x + 0.044715f * x * x * x);
  return __fdividef(x, 1.f + __expf(-2.f * u));
}

#define GLOBAL_TO_LDS16(gp, lp)                                                   \
  __builtin_amdgcn_global_load_lds((const __attribute__((address_space(1))) void*)(gp), \
                                   (__attribute__((address_space(3))) void*)(lp), 16, 0, 0)

// ---------------- fused transpose+cast for w1 and w2 ----------------
// fp32 [E][Rr][Cc] -> bf16 [E][Cc][Rr]. float4 loads, 16B bf16 stores.
__global__ __launch_bounds__(256) void transpose_cast_both(const float* __restrict__ w1,
                                                           const float* __restrict__ w2,
                                                           __hip_bfloat16* __restrict__ w1t,
                                                           __hip_bfloat16* __restrict__ w2t) {
  __shared__ __hip_bfloat16 tile[64 * 66];
  int bid = blockIdx.x;
  const float* in; __hip_bfloat16* outp; int Rr, Cc;
  if (bid < NEXP * 1024) { in = w1; outp = w1t; Rr = DDIM; Cc = FDIM; }
  else { bid -= NEXP * 1024; in = w2; outp = w2t; Rr = FDIM; Cc = DDIM; }
  int tilesC = Cc >> 6;
  int per = (Rr >> 6) * tilesC;  // == 1024
  int e = bid / per, rem = bid % per;
  int tr = rem / tilesC, tc = rem % tilesC;
  const float* ip = in + (size_t)e * Rr * Cc + (size_t)(tr * 64) * Cc + tc * 64;
  __hip_bfloat16* op = outp + (size_t)e * Rr * Cc + (size_t)(tc * 64) * Rr + tr * 64;
  int tid = threadIdx.x;
  int lrow = tid >> 4, lcol = (tid & 15) * 4;
#pragma unroll
  for (int p = 0; p < 4; p++) {
    int r = p * 16 + lrow;
    float4 v = *(const float4*)(ip + (size_t)r * Cc + lcol);
    tile[r * 66 + lcol + 0] = __float2bfloat16(v.x);
    tile[r * 66 + lcol + 1] = __float2bfloat16(v.y);
    tile[r * 66 + lcol + 2] = __float2bfloat16(v.z);
    tile[r * 66 + lcol + 3] = __float2bfloat16(v.w);
  }
  __syncthreads();
  int orow_l = tid >> 3, ocol = (tid & 7) * 8;
#pragma unroll
  for (int p = 0; p < 2; p++) {
    int orow = p * 32 + orow_l;  // output row == original column
    union { __hip_bfloat16 h[8]; uint4 u; } pk;
#pragma unroll
    for (int j = 0; j < 8; j++) pk.h[j] = tile[(ocol + j) * 66 + orow];
    *(uint4*)(op + (size_t)orow * Rr + ocol) = pk.u;
  }
}

// ---------------- router: logits -> top2 -> gates + slot assignment ----------------
__global__ __launch_bounds__(256) void router_kernel(const float* __restrict__ x,
                                                     const float* __restrict__ rw,
                                                     int* __restrict__ counts,
                                                     int* __restrict__ pair_e,
                                                     int* __restrict__ pair_slot,
                                                     float* __restrict__ pair_gate) {
  int lane = threadIdx.x & 63;
  int wid = threadIdx.x >> 6;
  int t = blockIdx.x * 4 + wid;  // one wave per token
  const float* xr = x + (size_t)t * DDIM;
  float acc[NEXP];
#pragma unroll
  for (int e = 0; e < NEXP; e++) acc[e] = 0.f;
  for (int d0 = lane * 4; d0 < DDIM; d0 += 256) {
    float4 xv = *(const float4*)(xr + d0);
    const float* r0 = rw + (size_t)d0 * NEXP;
#pragma unroll
    for (int e = 0; e < NEXP; e++)
      acc[e] += xv.x * r0[e] + xv.y * r0[NEXP + e] + xv.z * r0[2 * NEXP + e] + xv.w * r0[3 * NEXP + e];
  }
#pragma unroll
  for (int e = 0; e < NEXP; e++) {
#pragma unroll
    for (int m = 32; m > 0; m >>= 1) acc[e] += __shfl_xor(acc[e], m, 64);
  }
  if (lane == 0) {
    int e1 = 0; float l1 = acc[0];
    for (int e = 1; e < NEXP; e++) if (acc[e] > l1) { l1 = acc[e]; e1 = e; }
    int e2 = -1; float l2 = -1e30f;
    for (int e = 0; e < NEXP; e++) { if (e == e1) continue; if (acc[e] > l2) { l2 = acc[e]; e2 = e; } }
    // renormalized top-2 softmax == softmax over the two logits
    float g1 = 1.f / (1.f + __expf(l2 - l1));
    float g2 = 1.f - g1;
    int s1 = atomicAdd(&counts[e1], 1);
    int s2 = atomicAdd(&counts[e2], 1);
    pair_e[2 * t] = e1;     pair_slot[2 * t] = s1;     pair_gate[2 * t] = g1;
    pair_e[2 * t + 1] = e2; pair_slot[2 * t + 1] = s2; pair_gate[2 * t + 1] = g2;
  }
}

// ---------------- gather: x rows -> expert-compacted bf16 Xg ----------------
__global__ __launch_bounds__(256) void gather_kernel(const float* __restrict__ x,
                                                     const int* __restrict__ counts,
                                                     const int* __restrict__ pair_e,
                                                     const int* __restrict__ pair_slot,
                                                     const float* __restrict__ pair_gate,
                                                     __hip_bfloat16* __restrict__ Xg,
                                                     int* __restrict__ trow,
                                                     float* __restrict__ row_gate) {
  int p = blockIdx.x;
  int t = p >> 1;
  int e = pair_e[p];
  int base = 0;
#pragma unroll
  for (int i = 0; i < NEXP; i++) base += (i < e) ? counts[i] : 0;
  int row = base + pair_slot[p];
  const float* xr = x + (size_t)t * DDIM;
  __hip_bfloat16* dst = Xg + (size_t)row * DDIM;
  int i = threadIdx.x * 4;
  float4 v = *(const float4*)(xr + i);
  union { ushort4 u; __hip_bfloat16 h[4]; } o;
  o.h[0] = __float2bfloat16(v.x);
  o.h[1] = __float2bfloat16(v.y);
  o.h[2] = __float2bfloat16(v.z);
  o.h[3] = __float2bfloat16(v.w);
  *(ushort4*)(dst + i) = o.u;
  if (threadIdx.x == 0) { trow[p] = row; row_gate[row] = pair_gate[p]; }
}

// ---------------- 256x256 8-phase bf16 MFMA GEMM, per-expert row ranges ----------------
// A: bf16 [RPAD][K] (expert-compacted). Bw: bf16 [E][N][K].
// LDS 128 KiB dynamic: A/B x 2 buffers x 2 K-halves; slot = 256 rows x 32 k (16 KiB).
// Chunk swizzle (involution, applied to global SOURCE and fragment READ; LDS write linear).
// Schedule ledger (steady state; iteration computes tiles 2i (buf0), 2i+1 (buf1); 2 load
// instr per STAGE):
//   entry invariant: tile2i.kh0 resident; 8 outstanding = {tile2i.kh1, tile(2i+1).kh0}
//   ph0 read b0.kh0            stage (2i+1).kh1.A  -> 10
//   ph1 read b0.kh0            stage (2i+1).kh1.B  -> 12, vmcnt(8): retire tile2i.kh1
//   ph2 read b0.kh1            stage (2i+2).kh0.A  -> 10
//   ph3 read b0.kh1            stage (2i+2).kh0.B  -> 12, vmcnt(8): retire (2i+1).kh0
//   ph4 read b1.kh0            stage (2i+2).kh1.A  -> 10
//   ph5 read b1.kh0            stage (2i+2).kh1.B  -> 12, vmcnt(8): retire (2i+1).kh1
//   ph6 read b1.kh1            stage (2i+3).kh0.A  -> 10
//   ph7 read b1.kh1            stage (2i+3).kh0.B  -> 12, vmcnt(8): retire (2i+2).kh0
// ds_read -> MFMA waits are COMPILER-MANAGED (progressive lgkmcnt(N)) so the LDS drain
// overlaps the matrix drain; WAR safety comes from the two barriers + data dependence
// (each phase's reads are consumed by its own MFMAs before the end barrier).
//   EPI=0: Hout = gelu(A@B) bf16.  EPI=1: Cout = gate*(A@B) fp32.

#define MF(MM, NN, AV, BV) \
  acc[MM][NN] = __builtin_amdgcn_mfma_f32_16x16x32_bf16(AV, BV, acc[MM][NN], 0, 0, 0)

#define STAGE_A(t, kh) do {                                                     \
    __hip_bfloat16* l_ = lds + ((((t) & 1) * 2 + (kh)) * 8192);                 \
    const __hip_bfloat16* g_ = Abase + (size_t)(t) * BK + (kh) * 32;            \
    GLOBAL_TO_LDS16(g_ + sOff0, l_ + ldst0);                                    \
    GLOBAL_TO_LDS16(g_ + sOff1, l_ + ldst1);                                    \
  } while (0)

#define STAGE_B(t, kh) do {                                                     \
    __hip_bfloat16* l_ = lds + 32768 + ((((t) & 1) * 2 + (kh)) * 8192);         \
    const __hip_bfloat16* g_ = Bbase + (size_t)(t) * BK + (kh) * 32;            \
    GLOBAL_TO_LDS16(g_ + sOff0, l_ + ldst0);                                    \
    GLOBAL_TO_LDS16(g_ + sOff1, l_ + ldst1);                                    \
  } while (0)

#define PHASE(T, KH, MH, ISSUE, ...) do {                                       \
    const __hip_bfloat16* As_ = lds + (((T) * 2 + (KH)) * 8192);                \
    const __hip_bfloat16* Bs_ = lds + 32768 + (((T) * 2 + (KH)) * 8192);        \
    bf16x8 a0_ = *(const bf16x8*)(As_ + offA[(MH) * 4 + 0]);                    \
    bf16x8 a1_ = *(const bf16x8*)(As_ + offA[(MH) * 4 + 1]);                    \
    bf16x8 a2_ = *(const bf16x8*)(As_ + offA[(MH) * 4 + 2]);                    \
    bf16x8 a3_ = *(const bf16x8*)(As_ + offA[(MH) * 4 + 3]);                    \
    if ((MH) == 0) {                                                            \
      vb0 = *(const bf16x8*)(Bs_ + offB[0]);                                    \
      vb1 = *(const bf16x8*)(Bs_ + offB[1]);                                    \
      vb2 = *(const bf16x8*)(Bs_ + offB[2]);                                    \
      vb3 = *(const bf16x8*)(Bs_ + offB[3]);                                    \
    }                                                                           \
    ISSUE;                                                                      \
    __VA_ARGS__;                                                                \
    __builtin_amdgcn_s_barrier();                                               \
    __builtin_amdgcn_s_setprio(1);                                              \
    MF((MH)*4+0, 0, a0_, vb0); MF((MH)*4+0, 1, a0_, vb1);                       \
    MF((MH)*4+0, 2, a0_, vb2); MF((MH)*4+0, 3, a0_, vb3);                       \
    MF((MH)*4+1, 0, a1_, vb0); MF((MH)*4+1, 1, a1_, vb1);                       \
    MF((MH)*4+1, 2, a1_, vb2); MF((MH)*4+1, 3, a1_, vb3);                       \
    MF((MH)*4+2, 0, a2_, vb0); MF((MH)*4+2, 1, a2_, vb1);                       \
    MF((MH)*4+2, 2, a2_, vb2); MF((MH)*4+2, 3, a2_, vb3);                       \
    MF((MH)*4+3, 0, a3_, vb0); MF((MH)*4+3, 1, a3_, vb1);                       \
    MF((MH)*4+3, 2, a3_, vb2); MF((MH)*4+3, 3, a3_, vb3);                       \
    __builtin_amdgcn_s_setprio(0);                                              \
    __builtin_amdgcn_s_barrier();                                               \
  } while (0)

template <int EPI>
__global__ __launch_bounds__(512, 2) void moe_gemm8(const __hip_bfloat16* __restrict__ A,
                                                    const __hip_bfloat16* __restrict__ Bw,
                                                    __hip_bfloat16* __restrict__ Hout,
                                                    float* __restrict__ Cout,
                                                    const int* __restrict__ counts,
                                                    const float* __restrict__ row_gate,
                                                    int K, int N) {
  extern __shared__ __align__(16) __hip_bfloat16 lds[];
  const int MT = T_TOK / BM;  // 32 worst-case m-tiles per expert
  const int NT = N / BN;

  // bijective XCD swizzle (m204 form; grids here are multiples of 8)
  int nwg = gridDim.x;
  int bid0 = blockIdx.x;
  int xcd = bid0 & 7, idx = bid0 >> 3;
  int qq = nwg >> 3, rr8 = nwg & 7;
  int wg = (xcd < rr8 ? xcd * (qq + 1) : rr8 * (qq + 1) + (xcd - rr8) * qq) + idx;

  int e = wg / (MT * NT);
  int rem = wg % (MT * NT);
  const int GM = 8;
  int width = GM * NT;
  int group = rem / width;
  int gm0 = group * GM;
  int gsize = (MT - gm0 < GM) ? (MT - gm0) : GM;
  int mt = gm0 + (rem % gsize);
  int nt = (rem % width) / gsize;

  int n_e = counts[e];
  if (mt * BM >= n_e) return;
  int row0 = 0;
#pragma unroll
  for (int i = 0; i < NEXP; i++) row0 += (i < e) ? counts[i] : 0;
  int m_start = row0 + mt * BM;
  int row_end = row0 + n_e;

  const __hip_bfloat16* Abase = A + (size_t)m_start * K;
  const __hip_bfloat16* Bbase = Bw + (size_t)e * N * K + (size_t)(nt * BN) * K;

  int tid = threadIdx.x;
  int lane = tid & 63, wid = tid >> 6;
  int wm = (wid >> 2) * 128, wn = (wid & 3) * 64;  // 2x4 wave grid, 128x64 each
  int lr = lane & 15, lc = lane >> 4;

  // staging thread pattern: 2 x global_load_lds(16B) per half-tile; source pre-swizzled
  int q0 = tid, q1 = 512 + tid;
  int r0 = q0 >> 2, c0 = (q0 & 3) ^ ((r0 >> 1) & 3);
  int r1 = q1 >> 2, c1 = (q1 & 3) ^ ((r1 >> 1) & 3);
  size_t sOff0 = (size_t)r0 * K + c0 * 8;
  size_t sOff1 = (size_t)r1 * K + c1 * 8;
  int ldst0 = (q0 & ~63) * 8;   // wave-uniform LDS dst (elements)
  int ldst1 = (q1 & ~63) * 8;

  // fragment read offsets within a slot (same swizzle involution)
  int offA[8], offB[4];
#pragma unroll
  for (int m = 0; m < 8; m++) { int R = wm + m * 16 + lr; offA[m] = R * 32 + ((lc ^ ((R >> 1) & 3)) << 3); }
#pragma unroll
  for (int n = 0; n < 4; n++) { int R = wn + n * 16 + lr; offB[n] = R * 32 + ((lc ^ ((R >> 1) & 3)) << 3); }

  f32x4 acc[8][4];
#pragma unroll
  for (int m = 0; m < 8; m++)
#pragma unroll
    for (int n = 0; n < 4; n++)
#pragma unroll
      for (int r = 0; r < 4; r++) acc[m][n][r] = 0.f;
  bf16x8 vb0 = {}, vb1 = {}, vb2 = {}, vb3 = {};

  // prologue: tiles 0 (both halves) + 1.kh0 issued; vmcnt(8) -> tile0.kh0 resident,
  // 8 outstanding = {tile0.kh1, tile1.kh0} == steady-state entry invariant
  STAGE_A(0, 0); STAGE_B(0, 0);
  STAGE_A(0, 1); STAGE_B(0, 1);
  STAGE_A(1, 0); STAGE_B(1, 0);
  asm volatile("s_waitcnt vmcnt(8)" ::: "memory");
  __builtin_amdgcn_s_barrier();

  int NIT = K / (2 * BK);  // >= 2 and even K-tile count for both GEMMs
  for (int it = 0; it < NIT - 1; ++it) {
    int t1 = 2 * it + 1;
    PHASE(0, 0, 0, STAGE_A(t1, 1));
    PHASE(0, 0, 1, STAGE_B(t1, 1), asm volatile("s_waitcnt vmcnt(8)" ::: "memory"));
    PHASE(0, 1, 0, STAGE_A(t1 + 1, 0));
    PHASE(0, 1, 1, STAGE_B(t1 + 1, 0), asm volatile("s_waitcnt vmcnt(8)" ::: "memory"));
    PHASE(1, 0, 0, STAGE_A(t1 + 1, 1));
    PHASE(1, 0, 1, STAGE_B(t1 + 1, 1), asm volatile("s_waitcnt vmcnt(8)" ::: "memory"));
    PHASE(1, 1, 0, STAGE_A(t1 + 2, 0));
    PHASE(1, 1, 1, STAGE_B(t1 + 2, 0), asm volatile("s_waitcnt vmcnt(8)" ::: "memory"));
  }
  {  // final iteration: only the last K-tile's second half remains to stage.
    // entry: 8 outstanding {tile(2i).kh1, tile(2i+1).kh0}; ph0/1 add tile(2i+1).kh1.
    int t1 = K / BK - 1;
    PHASE(0, 0, 0, STAGE_A(t1, 1));
    PHASE(0, 0, 1, STAGE_B(t1, 1), asm volatile("s_waitcnt vmcnt(8)" ::: "memory"));
    PHASE(0, 1, 0, ((void)0));
    PHASE(0, 1, 1, ((void)0), asm volatile("s_waitcnt vmcnt(4)" ::: "memory"));
    PHASE(1, 0, 0, ((void)0));
    PHASE(1, 0, 1, ((void)0), asm volatile("s_waitcnt vmcnt(0)" ::: "memory"));
    PHASE(1, 1, 0, ((void)0));
    PHASE(1, 1, 1, ((void)0));
  }

  // epilogue; C/D layout: col = lane&15, row = (lane>>4)*4 + reg  [m89-verified]
  int quad = lc * 4;
#pragma unroll
  for (int m = 0; m < 8; m++) {
#pragma unroll
    for (int r = 0; r < 4; r++) {
      int grow = m_start + wm + m * 16 + quad + r;
      if (grow < row_end) {
        size_t basei = (size_t)grow * N + nt * BN + wn + lr;
        if (EPI == 0) {
#pragma unroll
          for (int n = 0; n < 4; n++)
            Hout[basei + n * 16] = __float2bfloat16(gelu_tanh(acc[m][n][r]));
        } else {
          float g = row_gate[grow];
#pragma unroll
          for (int n = 0; n < 4; n++)
            Cout[basei + n * 16] = g * acc[m][n][r];
        }
      }
    }
  }
}

// ---------------- combine: out[t] = P[row1] + P[row2] (gates pre-applied) ----------------
__global__ __launch_bounds__(256) void combine_kernel(const float* __restrict__ P,
                                                      const int* __restrict__ trow,
                                                      float* __restrict__ out) {
  int t = blockIdx.x;
  int r1 = trow[2 * t], r2 = trow[2 * t + 1];
  int d = threadIdx.x * 4;
  float4 a = *(const float4*)(P + (size_t)r1 * DDIM + d);
  float4 b = *(const float4*)(P + (size_t)r2 * DDIM + d);
  float4 o;
  o.x = a.x + b.x; o.y = a.y + b.y; o.z = a.z + b.z; o.w = a.w + b.w;
  *(float4*)(out + (size_t)t * DDIM + d) = o;
}

extern "C" void kernel_launch(void* const* d_in, const int* in_sizes, int n_in,
                              void* d_out, int out_size, void* d_ws, size_t ws_size,
                              hipStream_t stream) {
  (void)in_sizes; (void)n_in; (void)out_size; (void)ws_size;
  const float* x  = (const float*)d_in[0];
  const float* rw = (const float*)d_in[1];
  const float* w1 = (const float*)d_in[2];
  const float* w2 = (const float*)d_in[3];
  float* out = (float*)d_out;

  char* ws = (char*)d_ws;
  size_t off = 0;
  auto alloc = [&](size_t bytes) -> char* {
    off = (off + 255) & ~(size_t)255;
    char* p = ws + off;
    off += bytes;
    return p;
  };
  int*   counts    = (int*)alloc(NEXP * 4);
  int*   pair_e    = (int*)alloc((size_t)RTOT * 4);
  int*   pair_slot = (int*)alloc((size_t)RTOT * 4);
  float* pair_gate = (float*)alloc((size_t)RTOT * 4);
  int*   trow      = (int*)alloc((size_t)RTOT * 4);
  float* row_gate  = (float*)alloc((size_t)RTOT * 4);
  __hip_bfloat16* Xg  = (__hip_bfloat16*)alloc((size_t)RPAD * DDIM * 2);
  __hip_bfloat16* w1t = (__hip_bfloat16*)alloc((size_t)NEXP * DDIM * FDIM * 2);
  __hip_bfloat16* w2t = (__hip_bfloat16*)alloc((size_t)NEXP * DDIM * FDIM * 2);
  __hip_bfloat16* H   = (__hip_bfloat16*)alloc((size_t)RPAD * FDIM * 2);
  // P aliases w1t: w1t is dead after GEMM1; both are 64+ MB. Every call rewrites
  // w1t (transpose) before GEMM1, and GEMM2 fully writes P before combine reads it.
  float* P = (float*)w1t;      // [RTOT][DDIM] fp32 gated partials

  // host-side attribute set; graph-capture-safe, cheap -> do it every call
  hipFuncSetAttribute(reinterpret_cast<const void*>(moe_gemm8<0>),
                      hipFuncAttributeMaxDynamicSharedMemorySize, 131072);
  hipFuncSetAttribute(reinterpret_cast<const void*>(moe_gemm8<1>),
                      hipFuncAttributeMaxDynamicSharedMemorySize, 131072);

  hipMemsetAsync(counts, 0, NEXP * 4, stream);

  transpose_cast_both<<<2 * NEXP * 1024, 256, 0, stream>>>(w1, w2, w1t, w2t);
  router_kernel<<<T_TOK / 4, 256, 0, stream>>>(x, rw, counts, pair_e, pair_slot, pair_gate);
  gather_kernel<<<RTOT, 256, 0, stream>>>(x, counts, pair_e, pair_slot, pair_gate, Xg, trow, row_gate);

  moe_gemm8<0><<<NEXP * (T_TOK / BM) * (FDIM / BN), 512, 131072, stream>>>(
      Xg, w1t, H, nullptr, counts, nullptr, DDIM, FDIM);
  moe_gemm8<1><<<NEXP * (T_TOK / BM) * (DDIM / BN), 512, 131072, stream>>>(
      H, w2t, nullptr, P, counts, row_gate, FDIM, DDIM);
  combine_kernel<<<T_TOK, 256, 0, stream>>>(P, trow, out);
}